// Round 6
// baseline (494.437 us; speedup 1.0000x reference)
//
#include <hip/hip_runtime.h>
#include <hip/hip_bf16.h>

typedef unsigned short u16;
typedef unsigned int   u32;
typedef __attribute__((ext_vector_type(4))) float  f32x4;
typedef __attribute__((ext_vector_type(8))) __bf16 bf16x8;

#define B_    4096
#define OBS_  512
#define DH_   1024
#define NEXP_ 8
#define DK_   256
#define DV_   1024

__device__ __forceinline__ float b2f(u32 lo16) {
  return __builtin_bit_cast(float, lo16 << 16);
}
__device__ __forceinline__ u16 f2b(float f) {   // RNE fp32 -> bf16
  u32 u = __builtin_bit_cast(u32, f);
  return (u16)((u + 0x7fffu + ((u >> 16) & 1u)) >> 16);
}
// async global->LDS, 16 B per lane; LDS dest = wave-uniform base + lane*16
__device__ __forceinline__ void gl_lds16(const u16* g, u16* l) {
  __builtin_amdgcn_global_load_lds(
      (__attribute__((address_space(1))) void*)(void*)g,
      (__attribute__((address_space(3))) void*)(void*)l,
      16, 0, 0);
}

// ---------------- merged prologue ----------------
// conv x + 7 weight transposes + wnq/cn (one launch, block-id segmented)
__device__ __forceinline__ void tconv_body(const float* __restrict__ in,
                                           u16* __restrict__ outp,
                                           int R, int C, int rem, int tid) {
  __shared__ float tile[32][33];
  int gxs = (C == 128) ? 2 : 5;            // log2(C/32)
  int c0 = (rem & ((1 << gxs) - 1)) * 32;
  int r0 = (rem >> gxs) * 32;
  int tx = tid & 31, ty = tid >> 5;        // (32, 8)
#pragma unroll
  for (int i = 0; i < 4; ++i)
    tile[ty + i * 8][tx] = in[(long)(r0 + ty + i * 8) * C + c0 + tx];
  __syncthreads();
#pragma unroll
  for (int i = 0; i < 4; ++i)
    outp[(long)(c0 + ty + i * 8) * R + r0 + tx] = f2b(tile[tx][ty + i * 8]);
}

__global__ __launch_bounds__(256)
void prep(const float* __restrict__ x,  u16* __restrict__ xb,
          const float* __restrict__ Wb1, u16* __restrict__ Wb1T,
          const float* __restrict__ Wb2, u16* __restrict__ Wb2T,
          const float* __restrict__ We1, u16* __restrict__ We1T,
          const float* __restrict__ We2, u16* __restrict__ We2T,
          const float* __restrict__ Wv,  u16* __restrict__ WvT,
          const float* __restrict__ Wt1, u16* __restrict__ Wt1T,
          const float* __restrict__ Wl,  u16* __restrict__ WlT,
          const float* __restrict__ Wq,  const float* __restrict__ bq,
          const float* __restrict__ bk,  const int* __restrict__ task,
          const float* __restrict__ Wk,  float* __restrict__ wnq,
          float* __restrict__ cn) {
  int tid = threadIdx.x;
  int bid = blockIdx.x;
  if (bid < 2048) {                         // conv x
    long i = ((long)bid * 256 + tid) * 4;
    float4 v = *(const float4*)(x + i);
    u16 o[4] = { f2b(v.x), f2b(v.y), f2b(v.z), f2b(v.w) };
    *(uint2*)(xb + i) = *(const uint2*)o;
    return;
  }
  bid -= 2048;
  if (bid < 512)  { tconv_body(Wb1, Wb1T, 512, 1024, bid, tid); return; }
  bid -= 512;
  if (bid < 1024) { tconv_body(Wb2, Wb2T, 1024, 1024, bid, tid); return; }
  bid -= 1024;
  if (bid < 8192) {
    int z = bid >> 10, rem = bid & 1023;
    tconv_body(We1 + (long)z * DH_ * DH_, We1T + (long)z * DH_ * DH_, 1024, 1024, rem, tid);
    return;
  }
  bid -= 8192;
  if (bid < 8192) {
    int z = bid >> 10, rem = bid & 1023;
    tconv_body(We2 + (long)z * DH_ * DH_, We2T + (long)z * DH_ * DH_, 1024, 1024, rem, tid);
    return;
  }
  bid -= 8192;
  if (bid < 8192) { tconv_body(Wv, WvT, 8192, 1024, bid, tid); return; }
  bid -= 8192;
  if (bid < 1024) { tconv_body(Wt1, Wt1T, 1024, 1024, bid, tid); return; }
  bid -= 1024;
  if (bid < 128)  { tconv_body(Wl, WlT, 1024, 128, bid, tid); return; }
  bid -= 128;
  // wnq / cn segment: q[j] = Wq[task][task][j] + bq[task][j]
  int t = *task;
  const float* qrow = Wq + (long)(t * 10 + t) * DK_;
  const float* brow = bq + (long)t * DK_;
  int lane = tid & 63;
  if (bid < 2048) {
    int row = bid * 4 + (tid >> 6);          // 0..8191 = n*DH + d
    const float* wr = Wk + (long)row * DK_;
    float s = 0.f;
#pragma unroll
    for (int i = 0; i < 4; ++i) {
      int j = lane + i * 64;
      s += wr[j] * (qrow[j] + brow[j]);
    }
    for (int off = 32; off; off >>= 1) s += __shfl_xor(s, off);
    if (lane == 0) wnq[row] = s;
  } else {
    int w = tid >> 6;
    for (int n = w; n < NEXP_; n += 4) {
      float s = 0.f;
#pragma unroll
      for (int i = 0; i < 4; ++i) {
        int j = lane + i * 64;
        s += bk[n * DK_ + j] * (qrow[j] + brow[j]);
      }
      for (int off = 32; off; off >>= 1) s += __shfl_xor(s, off);
      if (lane == 0) cn[n] = s;
    }
  }
}

// ---------------- MFMA GEMM, 128x128 tile, 4 waves, BK=64 ----------------
// Proven config (r4): 968 TF, SQ_LDS_BANK_CONFLICT=0, 4 blocks/CU.
// XOR-swizzled LDS (physical colblock = c ^ (row&7)), stride 64 u16.
// OUT==0: bf16 out + optional bias/relu (+EKQ atomic row-dot).
// OUT==1: fp32 partial (split-K).
// EKQ==1: epilogue accumulates ekqOut[batch][row] += sum_col v*wnq[batch][col]
//         via intra-wave shfl over the 16 lr lanes + global atomicAdd.
template<int RELU, int OUT, int EKQ, int LDA, int LDB>
__global__ __launch_bounds__(256, 4)
void gemm_bt(const u16* __restrict__ A, const u16* __restrict__ Bt,
             const float* __restrict__ bias, void* __restrict__ Cv,
             int M, int N, int kper, int ksplit,
             long aB, long bB, long biasB, long cB,
             const float* __restrict__ wnq, float* __restrict__ ekqOut) {
  const int zz = blockIdx.z;
  const int split = zz % ksplit;
  const int batch = zz / ksplit;
  A  += (long)batch * aB + (long)split * kper;
  Bt += (long)batch * bB + (long)split * kper;

  int m_idx = blockIdx.y, n_idx = blockIdx.x;
  if (gridDim.x == 8) {                       // XCD swizzle, 256-block plane
    int f = blockIdx.x + (blockIdx.y << 3);
    int xcd = f & 7, j = f >> 3;
    n_idx = j & 7;
    m_idx = (xcd << 2) | (j >> 3);
  }
  const int m0 = m_idx * 128, n0 = n_idx * 128;

  __shared__ u16 As[128 * 64];
  __shared__ u16 Bs[128 * 64];
  const int tid  = threadIdx.x;
  const int lane = tid & 63, wid = tid >> 6;
  const int wm = (wid >> 1) * 64, wn = (wid & 1) * 64;
  const int lr = lane & 15, quad = lane >> 4;
  const int srow = lane >> 3;
  const int scol = ((lane & 7) ^ srow) * 8;

  const u16* ap0 = A  + (long)(m0 + wid * 32 +  0 + srow) * LDA + scol;
  const u16* ap1 = A  + (long)(m0 + wid * 32 +  8 + srow) * LDA + scol;
  const u16* ap2 = A  + (long)(m0 + wid * 32 + 16 + srow) * LDA + scol;
  const u16* ap3 = A  + (long)(m0 + wid * 32 + 24 + srow) * LDA + scol;
  const u16* bp0 = Bt + (long)(n0 + wid * 32 +  0 + srow) * LDB + scol;
  const u16* bp1 = Bt + (long)(n0 + wid * 32 +  8 + srow) * LDB + scol;
  const u16* bp2 = Bt + (long)(n0 + wid * 32 + 16 + srow) * LDB + scol;
  const u16* bp3 = Bt + (long)(n0 + wid * 32 + 24 + srow) * LDB + scol;
  u16* la = &As[wid * 2048];
  u16* lb = &Bs[wid * 2048];

  const int rsw = lr & 7;
  const int aB0 = (wm + lr) * 64 + ((quad    ) ^ rsw) * 8;
  const int aB1 = (wm + lr) * 64 + ((quad + 4) ^ rsw) * 8;
  const int bB0 = (wn + lr) * 64 + ((quad    ) ^ rsw) * 8;
  const int bB1 = (wn + lr) * 64 + ((quad + 4) ^ rsw) * 8;

  f32x4 acc[4][4] = {};

  for (int k0 = 0; k0 < kper; k0 += 64) {
    __syncthreads();
    gl_lds16(ap0 + k0, la);        gl_lds16(ap1 + k0, la + 512);
    gl_lds16(ap2 + k0, la + 1024); gl_lds16(ap3 + k0, la + 1536);
    gl_lds16(bp0 + k0, lb);        gl_lds16(bp1 + k0, lb + 512);
    gl_lds16(bp2 + k0, lb + 1024); gl_lds16(bp3 + k0, lb + 1536);
    __syncthreads();
#pragma unroll
    for (int h = 0; h < 2; ++h) {
      const int ab = h ? aB1 : aB0, bb = h ? bB1 : bB0;
      bf16x8 af[4], bfr[4];
#pragma unroll
      for (int i = 0; i < 4; ++i) af[i]  = *(const bf16x8*)(&As[ab + i * 1024]);
#pragma unroll
      for (int i = 0; i < 4; ++i) bfr[i] = *(const bf16x8*)(&Bs[bb + i * 1024]);
#pragma unroll
      for (int mi = 0; mi < 4; ++mi)
#pragma unroll
        for (int ni = 0; ni < 4; ++ni)
          acc[mi][ni] = __builtin_amdgcn_mfma_f32_16x16x32_bf16(af[mi], bfr[ni], acc[mi][ni], 0, 0, 0);
    }
  }

  // epilogue: C/D layout col=lane&15, row=quad*4+reg (verified m89/m91)
  if (OUT == 1) {
    float* C = (float*)Cv + (long)split * ((long)M * N);
#pragma unroll
    for (int mi = 0; mi < 4; ++mi)
#pragma unroll
      for (int ni = 0; ni < 4; ++ni) {
        int col = n0 + wn + ni * 16 + lr;
#pragma unroll
        for (int r = 0; r < 4; ++r) {
          int row = m0 + wm + mi * 16 + quad * 4 + r;
          C[(long)row * N + col] = acc[mi][ni][r];
        }
      }
  } else {
    u16* C = (u16*)Cv + (long)batch * cB;
    const float* bptr = bias ? bias + (long)batch * biasB : nullptr;
#pragma unroll
    for (int mi = 0; mi < 4; ++mi) {
      float psum[4] = {0.f, 0.f, 0.f, 0.f};
#pragma unroll
      for (int ni = 0; ni < 4; ++ni) {
        int col = n0 + wn + ni * 16 + lr;
        float bcol = bptr ? bptr[col] : 0.f;
        float wq = EKQ ? wnq[(long)batch * N + col] : 0.f;
#pragma unroll
        for (int r = 0; r < 4; ++r) {
          int row = m0 + wm + mi * 16 + quad * 4 + r;
          float v = acc[mi][ni][r] + bcol;
          if (RELU) v = fmaxf(v, 0.f);
          C[(long)row * N + col] = f2b(v);
          if (EKQ) psum[r] += v * wq;
        }
      }
      if (EKQ) {
#pragma unroll
        for (int r = 0; r < 4; ++r) {
          float s = psum[r];
          s += __shfl_xor(s, 1); s += __shfl_xor(s, 2);
          s += __shfl_xor(s, 4); s += __shfl_xor(s, 8);
          if (lr == 0)
            atomicAdd(ekqOut + (long)batch * M + (m0 + wm + mi * 16 + quad * 4 + r), s);
        }
      }
    }
  }
}

// ---------------- reduce 2 fp32 partials + bias + relu -> bf16 ----------------
__global__ __launch_bounds__(256)
void reduce2_relu(const float* __restrict__ part, const float* __restrict__ bias,
                  u16* __restrict__ outp, int N, long stride) {
  long f4 = ((long)blockIdx.x * 256 + threadIdx.x) * 4;
  float4 v0 = *(const float4*)(part + f4);
  float4 v1 = *(const float4*)(part + stride + f4);
  int col = (int)(f4 % N);
  float4 bb = *(const float4*)(bias + col);
  u16 o[4];
  o[0] = f2b(fmaxf(v0.x + v1.x + bb.x, 0.f));
  o[1] = f2b(fmaxf(v0.y + v1.y + bb.y, 0.f));
  o[2] = f2b(fmaxf(v0.z + v1.z + bb.z, 0.f));
  o[3] = f2b(fmaxf(v0.w + v1.w + bb.w, 0.f));
  *(uint2*)(outp + f4) = *(const uint2*)o;
}

// ------------- res[b,v] = bf16( sum_n (ekq[n,b]+cn[n]) * (y[n,b,v] + bv[n,v]) ) -------------
__global__ __launch_bounds__(256)
void reduce_res(const u16* __restrict__ y, const float* __restrict__ ekq,
                const float* __restrict__ cn, const float* __restrict__ bvp,
                u16* __restrict__ res) {
  long f8 = ((long)blockIdx.x * 256 + threadIdx.x) * 8;   // over B_*DV_
  int b = (int)(f8 >> 10);
  int v = (int)(f8 & (DV_ - 1));
  float acc[8] = {};
#pragma unroll
  for (int n = 0; n < NEXP_; ++n) {
    float s = ekq[n * B_ + b] + cn[n];
    uint4 p = *(const uint4*)(y + ((long)(n * B_ + b) * DV_) + v);
    const u32* pi = (const u32*)&p;
    float4 b0 = *(const float4*)(bvp + n * DV_ + v);
    float4 b1 = *(const float4*)(bvp + n * DV_ + v + 4);
    acc[0] += s * (b2f(pi[0] & 0xffffu) + b0.x);
    acc[1] += s * (b2f(pi[0] >> 16)     + b0.y);
    acc[2] += s * (b2f(pi[1] & 0xffffu) + b0.z);
    acc[3] += s * (b2f(pi[1] >> 16)     + b0.w);
    acc[4] += s * (b2f(pi[2] & 0xffffu) + b1.x);
    acc[5] += s * (b2f(pi[2] >> 16)     + b1.y);
    acc[6] += s * (b2f(pi[3] & 0xffffu) + b1.z);
    acc[7] += s * (b2f(pi[3] >> 16)     + b1.w);
  }
  u16 o[8];
#pragma unroll
  for (int i = 0; i < 8; ++i) o[i] = f2b(acc[i]);
  *(uint4*)(res + f8) = *(const uint4*)o;
}

// ---------------- reduce 8 Wl partials + bl, then split/clip/exp ----------------
__global__ __launch_bounds__(256)
void reduce_final(const float* __restrict__ part, const float* __restrict__ bl,
                  float* __restrict__ outp) {
  int flat = blockIdx.x * 256 + threadIdx.x;   // 4096*128
  int c = flat & 127, b = flat >> 7;
  float v = bl[c];
  const long S = (long)B_ * 128;
#pragma unroll
  for (int s = 0; s < 8; ++s) v += part[s * S + flat];
  if (c < 64) {
    outp[b * 64 + c] = v;                                  // mean
  } else {
    int i = b * 64 + (c - 64);
    float ls = fminf(fmaxf(v, -20.f), 2.f);
    outp[262144 + i] = expf(ls);                           // std
    outp[524288 + i] = ls;                                 // log_std
  }
}

extern "C" void kernel_launch(void* const* d_in, const int* in_sizes, int n_in,
                              void* d_out, int out_size, void* d_ws, size_t ws_size,
                              hipStream_t stream) {
  const float* x   = (const float*)d_in[0];
  const int*   task= (const int*)  d_in[1];
  const float* Wb1 = (const float*)d_in[2];
  const float* bb1 = (const float*)d_in[3];
  const float* Wb2 = (const float*)d_in[4];
  const float* bb2 = (const float*)d_in[5];
  const float* We1 = (const float*)d_in[6];
  const float* be1 = (const float*)d_in[7];
  const float* We2 = (const float*)d_in[8];
  const float* be2 = (const float*)d_in[9];
  const float* Wv  = (const float*)d_in[10];
  const float* bv  = (const float*)d_in[11];
  const float* Wk  = (const float*)d_in[12];
  const float* bk  = (const float*)d_in[13];
  const float* Wq  = (const float*)d_in[14];
  const float* bq  = (const float*)d_in[15];
  const float* Wt1 = (const float*)d_in[16];
  const float* bt1 = (const float*)d_in[17];
  const float* Wl  = (const float*)d_in[18];
  const float* bl  = (const float*)d_in[19];
  float* outp = (float*)d_out;

  char* ws = (char*)d_ws;
  size_t off = 0;
  auto alloc = [&](size_t bytes) -> char* {
    char* p = ws + off;
    off += (bytes + 255) & ~(size_t)255;
    return p;
  };

  u16* xb    = (u16*)alloc((size_t)B_ * OBS_ * 2);
  u16* Wb1T  = (u16*)alloc((size_t)DH_ * OBS_ * 2);
  u16* Wb2T  = (u16*)alloc((size_t)DH_ * DH_ * 2);
  u16* We1T  = (u16*)alloc((size_t)NEXP_ * DH_ * DH_ * 2);
  u16* We2T  = (u16*)alloc((size_t)NEXP_ * DH_ * DH_ * 2);
  u16* WvT   = (u16*)alloc((size_t)DV_ * NEXP_ * DH_ * 2);   // [DV][N*DH]
  u16* Wt1T  = (u16*)alloc((size_t)DH_ * DV_ * 2);
  u16* WlT   = (u16*)alloc((size_t)128 * DH_ * 2);
  u16* h1    = (u16*)alloc((size_t)B_ * DH_ * 2);
  u16* h     = (u16*)alloc((size_t)B_ * DH_ * 2);
  u16* e1    = (u16*)alloc((size_t)NEXP_ * B_ * DH_ * 2);    // 64 MB region
  u16* e2    = (u16*)alloc((size_t)NEXP_ * B_ * DH_ * 2);    // 64 MB region
  float* cn  = (float*)alloc(NEXP_ * 4);
  float* wnq = (float*)alloc((size_t)NEXP_ * DH_ * 4);
  float* ekq = (float*)alloc((size_t)NEXP_ * B_ * 4);
  // region reuse (dead by the time they're re-purposed; in-order stream):
  float* partA = (float*)e1;     // h1/h split-K partials (2 x 16 MB fp32)
  u16*   y     = e1;             // y[n][b][v] bf16 (e1 dead after e2 GEMM)
  u16*   res   = h1;             // res [B][DV]  (h1 dead after h GEMM)
  u16*   tt    = h;              // t   [B][DH]  (h dead after e1 GEMM)
  float* partB = (float*)e2;     // Wt1 / Wl split-K partials (e2 dead after y GEMM)

  // zero ekq accumulator (atomics target); memset node is graph-capture safe
  hipMemsetAsync(ekq, 0, (size_t)NEXP_ * B_ * 4, stream);
  // prologue: converts + transposes + wnq/cn, single launch
  prep<<<31361, 256, 0, stream>>>(x, xb, Wb1, Wb1T, Wb2, Wb2T, We1, We1T,
                                  We2, We2T, Wv, WvT, Wt1, Wt1T, Wl, WlT,
                                  Wq, bq, bk, task, Wk, wnq, cn);

  const long S1 = (long)B_ * DH_;
  // h1 = relu(x@Wb1+bb1)   [split-K 2]
  gemm_bt<0, 1, 0, OBS_, OBS_><<<dim3(8, 32, 2), 256, 0, stream>>>(xb, Wb1T, nullptr, partA,
      B_, DH_, 256, 2, 0, 0, 0, 0, nullptr, nullptr);
  reduce2_relu<<<4096, 256, 0, stream>>>(partA, bb1, h1, DH_, S1);
  // h = relu(h1@Wb2+bb2)   [split-K 2]
  gemm_bt<0, 1, 0, DH_, DH_><<<dim3(8, 32, 2), 256, 0, stream>>>(h1, Wb2T, nullptr, partA,
      B_, DH_, 512, 2, 0, 0, 0, 0, nullptr, nullptr);
  reduce2_relu<<<4096, 256, 0, stream>>>(partA, bb2, h, DH_, S1);
  // e1 = relu(h@We1+be1)   (128x128 tile, batched over experts)
  gemm_bt<1, 0, 0, DH_, DH_><<<dim3(8, 32, 8), 256, 0, stream>>>(h, We1T, be1, e1,
      B_, DH_, DH_, 1, 0, (long)DH_ * DH_, DH_, (long)B_ * DH_, nullptr, nullptr);
  // e2 = relu(e1@We2+be2), epilogue also accumulates ekq via atomics
  gemm_bt<1, 0, 1, DH_, DH_><<<dim3(8, 32, 8), 256, 0, stream>>>(e1, We2T, be2, e2,
      B_, DH_, DH_, 1, (long)B_ * DH_, (long)DH_ * DH_, DH_, (long)B_ * DH_, wnq, ekq);
  // y[n] = e2_n @ Wv_n  (per-expert B slice of WvT)
  gemm_bt<0, 0, 0, DH_, NEXP_ * DH_><<<dim3(8, 32, 8), 256, 0, stream>>>(e2, WvT, nullptr, y,
      B_, DV_, DH_, 1, (long)B_ * DH_, DH_, 0, (long)B_ * DV_, nullptr, nullptr);
  // res = sum_n (ekq+cn) * (y + bv)
  reduce_res<<<2048, 256, 0, stream>>>(y, ekq, cn, bv, res);
  // tower: t = relu(res@Wt1+bt1)   [split-K 2]
  gemm_bt<0, 1, 0, DV_, DV_><<<dim3(8, 32, 2), 256, 0, stream>>>(res, Wt1T, nullptr, partB,
      B_, DH_, 512, 2, 0, 0, 0, 0, nullptr, nullptr);
  reduce2_relu<<<4096, 256, 0, stream>>>(partB, bt1, tt, DH_, S1);
  // last: out = t@Wl   [split-K 8, N=128]
  gemm_bt<0, 1, 0, DH_, DH_><<<dim3(1, 32, 8), 256, 0, stream>>>(tt, WlT, nullptr, partB,
      B_, 128, 128, 8, 0, 0, 0, 0, nullptr, nullptr);
  reduce_final<<<(B_ * 128) / 256, 256, 0, stream>>>(partB, bl, outp);
}

// Round 7
// 457.956 us; speedup vs baseline: 1.0797x; 1.0797x over previous
//
#include <hip/hip_runtime.h>
#include <hip/hip_bf16.h>

typedef unsigned short u16;
typedef unsigned int   u32;
typedef __attribute__((ext_vector_type(4))) float  f32x4;
typedef __attribute__((ext_vector_type(8))) __bf16 bf16x8;

#define B_    4096
#define OBS_  512
#define DH_   1024
#define NEXP_ 8
#define DK_   256
#define DV_   1024

__device__ __forceinline__ float b2f(u32 lo16) {
  return __builtin_bit_cast(float, lo16 << 16);
}
__device__ __forceinline__ u16 f2b(float f) {   // RNE fp32 -> bf16
  u32 u = __builtin_bit_cast(u32, f);
  return (u16)((u + 0x7fffu + ((u >> 16) & 1u)) >> 16);
}
// async global->LDS, 16 B per lane; LDS dest = wave-uniform base + lane*16
__device__ __forceinline__ void gl_lds16(const u16* g, u16* l) {
  __builtin_amdgcn_global_load_lds(
      (__attribute__((address_space(1))) void*)(void*)g,
      (__attribute__((address_space(3))) void*)(void*)l,
      16, 0, 0);
}

// ---------------- merged prologue ----------------
// conv x + 7 weight transposes + wnq/cn (one launch, block-id segmented)
__device__ __forceinline__ void tconv_body(const float* __restrict__ in,
                                           u16* __restrict__ outp,
                                           int R, int C, int rem, int tid) {
  __shared__ float tile[32][33];
  int gxs = (C == 128) ? 2 : 5;            // log2(C/32)
  int c0 = (rem & ((1 << gxs) - 1)) * 32;
  int r0 = (rem >> gxs) * 32;
  int tx = tid & 31, ty = tid >> 5;        // (32, 8)
#pragma unroll
  for (int i = 0; i < 4; ++i)
    tile[ty + i * 8][tx] = in[(long)(r0 + ty + i * 8) * C + c0 + tx];
  __syncthreads();
#pragma unroll
  for (int i = 0; i < 4; ++i)
    outp[(long)(c0 + ty + i * 8) * R + r0 + tx] = f2b(tile[tx][ty + i * 8]);
}

__global__ __launch_bounds__(256)
void prep(const float* __restrict__ x,  u16* __restrict__ xb,
          const float* __restrict__ Wb1, u16* __restrict__ Wb1T,
          const float* __restrict__ Wb2, u16* __restrict__ Wb2T,
          const float* __restrict__ We1, u16* __restrict__ We1T,
          const float* __restrict__ We2, u16* __restrict__ We2T,
          const float* __restrict__ Wv,  u16* __restrict__ WvT,
          const float* __restrict__ Wt1, u16* __restrict__ Wt1T,
          const float* __restrict__ Wl,  u16* __restrict__ WlT,
          const float* __restrict__ Wq,  const float* __restrict__ bq,
          const float* __restrict__ bk,  const int* __restrict__ task,
          const float* __restrict__ Wk,  float* __restrict__ wnq,
          float* __restrict__ cn) {
  int tid = threadIdx.x;
  int bid = blockIdx.x;
  if (bid < 2048) {                         // conv x
    long i = ((long)bid * 256 + tid) * 4;
    float4 v = *(const float4*)(x + i);
    u16 o[4] = { f2b(v.x), f2b(v.y), f2b(v.z), f2b(v.w) };
    *(uint2*)(xb + i) = *(const uint2*)o;
    return;
  }
  bid -= 2048;
  if (bid < 512)  { tconv_body(Wb1, Wb1T, 512, 1024, bid, tid); return; }
  bid -= 512;
  if (bid < 1024) { tconv_body(Wb2, Wb2T, 1024, 1024, bid, tid); return; }
  bid -= 1024;
  if (bid < 8192) {
    int z = bid >> 10, rem = bid & 1023;
    tconv_body(We1 + (long)z * DH_ * DH_, We1T + (long)z * DH_ * DH_, 1024, 1024, rem, tid);
    return;
  }
  bid -= 8192;
  if (bid < 8192) {
    int z = bid >> 10, rem = bid & 1023;
    tconv_body(We2 + (long)z * DH_ * DH_, We2T + (long)z * DH_ * DH_, 1024, 1024, rem, tid);
    return;
  }
  bid -= 8192;
  if (bid < 8192) { tconv_body(Wv, WvT, 8192, 1024, bid, tid); return; }
  bid -= 8192;
  if (bid < 1024) { tconv_body(Wt1, Wt1T, 1024, 1024, bid, tid); return; }
  bid -= 1024;
  if (bid < 128)  { tconv_body(Wl, WlT, 1024, 128, bid, tid); return; }
  bid -= 128;
  // wnq / cn segment: q[j] = Wq[task][task][j] + bq[task][j]
  int t = *task;
  const float* qrow = Wq + (long)(t * 10 + t) * DK_;
  const float* brow = bq + (long)t * DK_;
  int lane = tid & 63;
  if (bid < 2048) {
    int row = bid * 4 + (tid >> 6);          // 0..8191 = n*DH + d
    const float* wr = Wk + (long)row * DK_;
    float s = 0.f;
#pragma unroll
    for (int i = 0; i < 4; ++i) {
      int j = lane + i * 64;
      s += wr[j] * (qrow[j] + brow[j]);
    }
    for (int off = 32; off; off >>= 1) s += __shfl_xor(s, off);
    if (lane == 0) wnq[row] = s;
  } else {
    int w = tid >> 6;
    for (int n = w; n < NEXP_; n += 4) {
      float s = 0.f;
#pragma unroll
      for (int i = 0; i < 4; ++i) {
        int j = lane + i * 64;
        s += bk[n * DK_ + j] * (qrow[j] + brow[j]);
      }
      for (int off = 32; off; off >>= 1) s += __shfl_xor(s, off);
      if (lane == 0) cn[n] = s;
    }
  }
}

// ---------------- MFMA GEMM, 128x128 tile, 4 waves, BK=64 ----------------
// Proven config (r4): 968 TF, SQ_LDS_BANK_CONFLICT=0, 4 blocks/CU.
// XOR-swizzled LDS (physical colblock = c ^ (row&7)), stride 64 u16.
// OUT==0: bf16 out + optional bias/relu. OUT==1: fp32 partial (split-K).
// EKQ==1: epilogue writes per-n-tile partial row-dots (NO device atomics —
// device-scope atomicAdd executes at the LLC on multi-XCD CDNA4, +10us on r6):
//   ekqPart[batch][n_idx][row] = sum over this block's 128 cols of v*wnq[col],
// waves pre-combined via a 1 KB LDS scratch carved from As.
template<int RELU, int OUT, int EKQ, int LDA, int LDB>
__global__ __launch_bounds__(256, 4)
void gemm_bt(const u16* __restrict__ A, const u16* __restrict__ Bt,
             const float* __restrict__ bias, void* __restrict__ Cv,
             int M, int N, int kper, int ksplit,
             long aB, long bB, long biasB, long cB,
             const float* __restrict__ wnq, float* __restrict__ ekqPart) {
  const int zz = blockIdx.z;
  const int split = zz % ksplit;
  const int batch = zz / ksplit;
  A  += (long)batch * aB + (long)split * kper;
  Bt += (long)batch * bB + (long)split * kper;

  int m_idx = blockIdx.y, n_idx = blockIdx.x;
  if (gridDim.x == 8) {                       // XCD swizzle, 256-block plane
    int f = blockIdx.x + (blockIdx.y << 3);
    int xcd = f & 7, j = f >> 3;
    n_idx = j & 7;
    m_idx = (xcd << 2) | (j >> 3);
  }
  const int m0 = m_idx * 128, n0 = n_idx * 128;

  __shared__ u16 As[128 * 64];
  __shared__ u16 Bs[128 * 64];
  const int tid  = threadIdx.x;
  const int lane = tid & 63, wid = tid >> 6;
  const int wm = (wid >> 1) * 64, wn = (wid & 1) * 64;
  const int lr = lane & 15, quad = lane >> 4;
  const int srow = lane >> 3;
  const int scol = ((lane & 7) ^ srow) * 8;

  const u16* ap0 = A  + (long)(m0 + wid * 32 +  0 + srow) * LDA + scol;
  const u16* ap1 = A  + (long)(m0 + wid * 32 +  8 + srow) * LDA + scol;
  const u16* ap2 = A  + (long)(m0 + wid * 32 + 16 + srow) * LDA + scol;
  const u16* ap3 = A  + (long)(m0 + wid * 32 + 24 + srow) * LDA + scol;
  const u16* bp0 = Bt + (long)(n0 + wid * 32 +  0 + srow) * LDB + scol;
  const u16* bp1 = Bt + (long)(n0 + wid * 32 +  8 + srow) * LDB + scol;
  const u16* bp2 = Bt + (long)(n0 + wid * 32 + 16 + srow) * LDB + scol;
  const u16* bp3 = Bt + (long)(n0 + wid * 32 + 24 + srow) * LDB + scol;
  u16* la = &As[wid * 2048];
  u16* lb = &Bs[wid * 2048];

  const int rsw = lr & 7;
  const int aB0 = (wm + lr) * 64 + ((quad    ) ^ rsw) * 8;
  const int aB1 = (wm + lr) * 64 + ((quad + 4) ^ rsw) * 8;
  const int bB0 = (wn + lr) * 64 + ((quad    ) ^ rsw) * 8;
  const int bB1 = (wn + lr) * 64 + ((quad + 4) ^ rsw) * 8;

  f32x4 acc[4][4] = {};

  for (int k0 = 0; k0 < kper; k0 += 64) {
    __syncthreads();
    gl_lds16(ap0 + k0, la);        gl_lds16(ap1 + k0, la + 512);
    gl_lds16(ap2 + k0, la + 1024); gl_lds16(ap3 + k0, la + 1536);
    gl_lds16(bp0 + k0, lb);        gl_lds16(bp1 + k0, lb + 512);
    gl_lds16(bp2 + k0, lb + 1024); gl_lds16(bp3 + k0, lb + 1536);
    __syncthreads();
#pragma unroll
    for (int h = 0; h < 2; ++h) {
      const int ab = h ? aB1 : aB0, bb = h ? bB1 : bB0;
      bf16x8 af[4], bfr[4];
#pragma unroll
      for (int i = 0; i < 4; ++i) af[i]  = *(const bf16x8*)(&As[ab + i * 1024]);
#pragma unroll
      for (int i = 0; i < 4; ++i) bfr[i] = *(const bf16x8*)(&Bs[bb + i * 1024]);
#pragma unroll
      for (int mi = 0; mi < 4; ++mi)
#pragma unroll
        for (int ni = 0; ni < 4; ++ni)
          acc[mi][ni] = __builtin_amdgcn_mfma_f32_16x16x32_bf16(af[mi], bfr[ni], acc[mi][ni], 0, 0, 0);
    }
  }

  // epilogue: C/D layout col=lane&15, row=quad*4+reg (verified m89/m91)
  if (OUT == 1) {
    float* C = (float*)Cv + (long)split * ((long)M * N);
#pragma unroll
    for (int mi = 0; mi < 4; ++mi)
#pragma unroll
      for (int ni = 0; ni < 4; ++ni) {
        int col = n0 + wn + ni * 16 + lr;
#pragma unroll
        for (int r = 0; r < 4; ++r) {
          int row = m0 + wm + mi * 16 + quad * 4 + r;
          C[(long)row * N + col] = acc[mi][ni][r];
        }
      }
  } else {
    u16* C = (u16*)Cv + (long)batch * cB;
    const float* bptr = bias ? bias + (long)batch * biasB : nullptr;
    float* eLds = (float*)As;                 // 4 waves x 64 rows (1 KB scratch)
    if (EKQ) __syncthreads();                 // all waves done reading As
#pragma unroll
    for (int mi = 0; mi < 4; ++mi) {
      float psum[4] = {0.f, 0.f, 0.f, 0.f};
#pragma unroll
      for (int ni = 0; ni < 4; ++ni) {
        int col = n0 + wn + ni * 16 + lr;
        float bcol = bptr ? bptr[col] : 0.f;
        float wq = EKQ ? wnq[(long)batch * N + col] : 0.f;
#pragma unroll
        for (int r = 0; r < 4; ++r) {
          int row = m0 + wm + mi * 16 + quad * 4 + r;
          float v = acc[mi][ni][r] + bcol;
          if (RELU) v = fmaxf(v, 0.f);
          C[(long)row * N + col] = f2b(v);
          if (EKQ) psum[r] += v * wq;
        }
      }
      if (EKQ) {
#pragma unroll
        for (int r = 0; r < 4; ++r) {
          float s = psum[r];
          s += __shfl_xor(s, 1); s += __shfl_xor(s, 2);
          s += __shfl_xor(s, 4); s += __shfl_xor(s, 8);
          if (lr == 0) eLds[wid * 64 + mi * 16 + quad * 4 + r] = s;
        }
      }
    }
    if (EKQ) {
      __syncthreads();
      if (tid < 128) {
        int half = tid >> 6, loc = tid & 63;        // rows 0-63: waves 0,1; 64-127: waves 2,3
        float v = eLds[half * 128 + loc] + eLds[half * 128 + 64 + loc];
        ekqPart[((long)batch * 8 + n_idx) * M + m0 + tid] = v;
      }
    }
  }
}

// ---------------- MFMA GEMM, 64x128 tile, 4 waves, no split-K (small GEMMs) ----------------
// 4 waves side-by-side in n (each 64m x 32n); fused bias+relu+bf16 out.
// Grid (N/128, M/64) = 512 blocks -> 2+ blocks/CU without split-K or reduce pass.
// Same XOR-swizzled BK=64 staging as gemm_bt (conflict-free, r4-verified).
template<int LDA, int LDB>
__global__ __launch_bounds__(256, 4)
void gemm_sm(const u16* __restrict__ A, const u16* __restrict__ Bt,
             const float* __restrict__ bias, u16* __restrict__ C,
             int N, int kper) {
  // XCD swizzle over the 512-block plane: each XCD owns 8 m-tiles, n fastest
  int f = blockIdx.x + (blockIdx.y << 3);
  int xcd = f & 7;
  const int n_idx = (f >> 3) & 7;
  const int m_idx = (xcd << 3) | (f >> 6);
  const int m0 = m_idx * 64, n0 = n_idx * 128;

  __shared__ u16 As[64 * 64];
  __shared__ u16 Bs[128 * 64];
  const int tid  = threadIdx.x;
  const int lane = tid & 63, wid = tid >> 6;
  const int wn = wid * 32;
  const int lr = lane & 15, quad = lane >> 4;
  const int srow = lane >> 3;
  const int scol = ((lane & 7) ^ srow) * 8;

  const u16* ap0 = A  + (long)(m0 + wid * 16 + 0 + srow) * LDA + scol;
  const u16* ap1 = A  + (long)(m0 + wid * 16 + 8 + srow) * LDA + scol;
  const u16* bp0 = Bt + (long)(n0 + wid * 32 +  0 + srow) * LDB + scol;
  const u16* bp1 = Bt + (long)(n0 + wid * 32 +  8 + srow) * LDB + scol;
  const u16* bp2 = Bt + (long)(n0 + wid * 32 + 16 + srow) * LDB + scol;
  const u16* bp3 = Bt + (long)(n0 + wid * 32 + 24 + srow) * LDB + scol;
  u16* la = &As[wid * 1024];
  u16* lb = &Bs[wid * 2048];

  const int rsw = lr & 7;
  const int aB0 = lr * 64 + ((quad    ) ^ rsw) * 8;
  const int aB1 = lr * 64 + ((quad + 4) ^ rsw) * 8;
  const int bB0 = (wn + lr) * 64 + ((quad    ) ^ rsw) * 8;
  const int bB1 = (wn + lr) * 64 + ((quad + 4) ^ rsw) * 8;

  f32x4 acc[4][2] = {};

  for (int k0 = 0; k0 < kper; k0 += 64) {
    __syncthreads();
    gl_lds16(ap0 + k0, la);        gl_lds16(ap1 + k0, la + 512);
    gl_lds16(bp0 + k0, lb);        gl_lds16(bp1 + k0, lb + 512);
    gl_lds16(bp2 + k0, lb + 1024); gl_lds16(bp3 + k0, lb + 1536);
    __syncthreads();
#pragma unroll
    for (int h = 0; h < 2; ++h) {
      const int ab = h ? aB1 : aB0, bb = h ? bB1 : bB0;
      bf16x8 af[4], bfr[2];
#pragma unroll
      for (int i = 0; i < 4; ++i) af[i]  = *(const bf16x8*)(&As[ab + i * 1024]);
#pragma unroll
      for (int i = 0; i < 2; ++i) bfr[i] = *(const bf16x8*)(&Bs[bb + i * 1024]);
#pragma unroll
      for (int mi = 0; mi < 4; ++mi)
#pragma unroll
        for (int ni = 0; ni < 2; ++ni)
          acc[mi][ni] = __builtin_amdgcn_mfma_f32_16x16x32_bf16(af[mi], bfr[ni], acc[mi][ni], 0, 0, 0);
    }
  }

#pragma unroll
  for (int mi = 0; mi < 4; ++mi)
#pragma unroll
    for (int ni = 0; ni < 2; ++ni) {
      int col = n0 + wn + ni * 16 + lr;
      float bcol = bias[col];
#pragma unroll
      for (int r = 0; r < 4; ++r) {
        int row = m0 + mi * 16 + quad * 4 + r;
        C[(long)row * N + col] = f2b(fmaxf(acc[mi][ni][r] + bcol, 0.f));
      }
    }
}

// -- res[b,v] = bf16( sum_n (cn[n]+sum_t ekqPart[n][t][b]) * (y[n,b,v]+bv[n,v]) ) --
__global__ __launch_bounds__(256)
void reduce_res(const u16* __restrict__ y, const float* __restrict__ ekqPart,
                const float* __restrict__ cn, const float* __restrict__ bvp,
                u16* __restrict__ res) {
  long f8 = ((long)blockIdx.x * 256 + threadIdx.x) * 8;   // over B_*DV_
  int b = (int)(f8 >> 10);
  int v = (int)(f8 & (DV_ - 1));
  float s[NEXP_];
#pragma unroll
  for (int n = 0; n < NEXP_; ++n) {
    float t = cn[n];
#pragma unroll
    for (int nt = 0; nt < 8; ++nt) t += ekqPart[((long)n * 8 + nt) * B_ + b];
    s[n] = t;
  }
  float acc[8] = {};
#pragma unroll
  for (int n = 0; n < NEXP_; ++n) {
    float sn = s[n];
    uint4 p = *(const uint4*)(y + ((long)(n * B_ + b) * DV_) + v);
    const u32* pi = (const u32*)&p;
    float4 b0 = *(const float4*)(bvp + n * DV_ + v);
    float4 b1 = *(const float4*)(bvp + n * DV_ + v + 4);
    acc[0] += sn * (b2f(pi[0] & 0xffffu) + b0.x);
    acc[1] += sn * (b2f(pi[0] >> 16)     + b0.y);
    acc[2] += sn * (b2f(pi[1] & 0xffffu) + b0.z);
    acc[3] += sn * (b2f(pi[1] >> 16)     + b0.w);
    acc[4] += sn * (b2f(pi[2] & 0xffffu) + b1.x);
    acc[5] += sn * (b2f(pi[2] >> 16)     + b1.y);
    acc[6] += sn * (b2f(pi[3] & 0xffffu) + b1.z);
    acc[7] += sn * (b2f(pi[3] >> 16)     + b1.w);
  }
  u16 o[8];
#pragma unroll
  for (int i = 0; i < 8; ++i) o[i] = f2b(acc[i]);
  *(uint4*)(res + f8) = *(const uint4*)o;
}

// ---------------- reduce 8 Wl partials + bl, then split/clip/exp ----------------
__global__ __launch_bounds__(256)
void reduce_final(const float* __restrict__ part, const float* __restrict__ bl,
                  float* __restrict__ outp) {
  int flat = blockIdx.x * 256 + threadIdx.x;   // 4096*128
  int c = flat & 127, b = flat >> 7;
  float v = bl[c];
  const long S = (long)B_ * 128;
#pragma unroll
  for (int s = 0; s < 8; ++s) v += part[s * S + flat];
  if (c < 64) {
    outp[b * 64 + c] = v;                                  // mean
  } else {
    int i = b * 64 + (c - 64);
    float ls = fminf(fmaxf(v, -20.f), 2.f);
    outp[262144 + i] = expf(ls);                           // std
    outp[524288 + i] = ls;                                 // log_std
  }
}

extern "C" void kernel_launch(void* const* d_in, const int* in_sizes, int n_in,
                              void* d_out, int out_size, void* d_ws, size_t ws_size,
                              hipStream_t stream) {
  const float* x   = (const float*)d_in[0];
  const int*   task= (const int*)  d_in[1];
  const float* Wb1 = (const float*)d_in[2];
  const float* bb1 = (const float*)d_in[3];
  const float* Wb2 = (const float*)d_in[4];
  const float* bb2 = (const float*)d_in[5];
  const float* We1 = (const float*)d_in[6];
  const float* be1 = (const float*)d_in[7];
  const float* We2 = (const float*)d_in[8];
  const float* be2 = (const float*)d_in[9];
  const float* Wv  = (const float*)d_in[10];
  const float* bv  = (const float*)d_in[11];
  const float* Wk  = (const float*)d_in[12];
  const float* bk  = (const float*)d_in[13];
  const float* Wq  = (const float*)d_in[14];
  const float* bq  = (const float*)d_in[15];
  const float* Wt1 = (const float*)d_in[16];
  const float* bt1 = (const float*)d_in[17];
  const float* Wl  = (const float*)d_in[18];
  const float* bl  = (const float*)d_in[19];
  float* outp = (float*)d_out;

  char* ws = (char*)d_ws;
  size_t off = 0;
  auto alloc = [&](size_t bytes) -> char* {
    char* p = ws + off;
    off += (bytes + 255) & ~(size_t)255;
    return p;
  };

  u16* xb    = (u16*)alloc((size_t)B_ * OBS_ * 2);
  u16* Wb1T  = (u16*)alloc((size_t)DH_ * OBS_ * 2);
  u16* Wb2T  = (u16*)alloc((size_t)DH_ * DH_ * 2);
  u16* We1T  = (u16*)alloc((size_t)NEXP_ * DH_ * DH_ * 2);
  u16* We2T  = (u16*)alloc((size_t)NEXP_ * DH_ * DH_ * 2);
  u16* WvT   = (u16*)alloc((size_t)DV_ * NEXP_ * DH_ * 2);   // [DV][N*DH]
  u16* Wt1T  = (u16*)alloc((size_t)DH_ * DV_ * 2);
  u16* WlT   = (u16*)alloc((size_t)128 * DH_ * 2);
  u16* h1    = (u16*)alloc((size_t)B_ * DH_ * 2);
  u16* h     = (u16*)alloc((size_t)B_ * DH_ * 2);
  u16* e1    = (u16*)alloc((size_t)NEXP_ * B_ * DH_ * 2);    // 64 MB region
  u16* e2    = (u16*)alloc((size_t)NEXP_ * B_ * DH_ * 2);    // 64 MB region
  float* cn  = (float*)alloc(NEXP_ * 4);
  float* wnq = (float*)alloc((size_t)NEXP_ * DH_ * 4);
  float* ekqPart = (float*)alloc((size_t)NEXP_ * 8 * B_ * 4);  // [n][n_tile][b], 1 MB
  // region reuse (dead by the time they're re-purposed; in-order stream):
  u16*   y     = e1;             // y[n][b][v] bf16 (e1 dead after e2 GEMM)
  u16*   res   = h1;             // res [B][DV]  (h1 dead after h GEMM)
  u16*   tt    = h;              // t   [B][DH]  (h dead after e1 GEMM)
  float* partB = (float*)e2;     // Wl split-K partials (e2 dead after y GEMM)

  // prologue: converts + transposes + wnq/cn, single launch
  prep<<<31361, 256, 0, stream>>>(x, xb, Wb1, Wb1T, Wb2, Wb2T, We1, We1T,
                                  We2, We2T, Wv, WvT, Wt1, Wt1T, Wl, WlT,
                                  Wq, bq, bk, task, Wk, wnq, cn);

  // h1 = relu(x@Wb1+bb1)          (64x128 tile, no split-K)
  gemm_sm<OBS_, OBS_><<<dim3(8, 64), 256, 0, stream>>>(xb, Wb1T, bb1, h1, DH_, OBS_);
  // h = relu(h1@Wb2+bb2)
  gemm_sm<DH_, DH_><<<dim3(8, 64), 256, 0, stream>>>(h1, Wb2T, bb2, h, DH_, DH_);
  // e1 = relu(h@We1+be1)          (128x128 tile, batched over experts)
  gemm_bt<1, 0, 0, DH_, DH_><<<dim3(8, 32, 8), 256, 0, stream>>>(h, We1T, be1, e1,
      B_, DH_, DH_, 1, 0, (long)DH_ * DH_, DH_, (long)B_ * DH_, nullptr, nullptr);
  // e2 = relu(e1@We2+be2), epilogue writes per-n-tile ekq partials (no atomics)
  gemm_bt<1, 0, 1, DH_, DH_><<<dim3(8, 32, 8), 256, 0, stream>>>(e1, We2T, be2, e2,
      B_, DH_, DH_, 1, (long)B_ * DH_, (long)DH_ * DH_, DH_, (long)B_ * DH_, wnq, ekqPart);
  // y[n] = e2_n @ Wv_n            (per-expert B slice of WvT)
  gemm_bt<0, 0, 0, DH_, NEXP_ * DH_><<<dim3(8, 32, 8), 256, 0, stream>>>(e2, WvT, nullptr, y,
      B_, DV_, DH_, 1, (long)B_ * DH_, DH_, 0, (long)B_ * DV_, nullptr, nullptr);
  // res = sum_n (cn + sum_t ekqPart) * (y + bv)
  reduce_res<<<2048, 256, 0, stream>>>(y, ekqPart, cn, bv, res);
  // tower: t = relu(res@Wt1+bt1)  (64x128 tile, no split-K)
  gemm_sm<DV_, DV_><<<dim3(8, 64), 256, 0, stream>>>(res, Wt1T, bt1, tt, DH_, DV_);
  // last: out = t@Wl              [split-K 8, N=128]
  gemm_bt<0, 1, 0, DH_, DH_><<<dim3(1, 32, 8), 256, 0, stream>>>(tt, WlT, nullptr, partB,
      B_, 128, 128, 8, 0, 0, 0, 0, nullptr, nullptr);
  reduce_final<<<(B_ * 128) / 256, 256, 0, stream>>>(partB, bl, outp);
}